// Round 1
// baseline (36.333 us; speedup 1.0000x reference)
//
#include <hip/hip_runtime.h>

// EmbeddingBag (SUM): out[b][d] = sum_k weight[input[b][k]][d]
// input: [16384, 50] int, weight: [1_000_000, 64] fp32, out: [16384, 64] fp32

#define EB_BATCH 16384
#define EB_BAG 50
#define EB_DIM 64

__global__ __launch_bounds__(256) void CompoundEmbedding_79989470921233_kernel(
    const int* __restrict__ idx, const float* __restrict__ weight,
    float* __restrict__ out) {
    const int tid = blockIdx.x * blockDim.x + threadIdx.x;  // 0 .. BATCH*16-1
    const int b  = tid >> 4;   // 16 threads per batch row
    const int dq = tid & 15;   // which float4 of the 64-dim row
    if (b >= EB_BATCH) return;

    const int* __restrict__ bag = idx + b * EB_BAG;
    float4 acc = make_float4(0.f, 0.f, 0.f, 0.f);

#pragma unroll 10
    for (int k = 0; k < EB_BAG; ++k) {
        const int r = bag[k];
        const float4 v = *reinterpret_cast<const float4*>(
            weight + (size_t)r * EB_DIM + (dq << 2));
        acc.x += v.x;
        acc.y += v.y;
        acc.z += v.z;
        acc.w += v.w;
    }

    reinterpret_cast<float4*>(out)[tid] = acc;  // byte offset b*256 + dq*16
}

extern "C" void kernel_launch(void* const* d_in, const int* in_sizes, int n_in,
                              void* d_out, int out_size, void* d_ws, size_t ws_size,
                              hipStream_t stream) {
    const int* idx = (const int*)d_in[0];          // input [16384, 50]
    const float* weight = (const float*)d_in[1];   // weight [1e6, 64]
    float* out = (float*)d_out;                    // [16384, 64]

    const int threads = 256;
    const int total = EB_BATCH * 16;               // 16 threads per batch row
    const int blocks = (total + threads - 1) / threads;  // 1024
    CompoundEmbedding_79989470921233_kernel<<<blocks, threads, 0, stream>>>(
        idx, weight, out);
}